// Round 2
// baseline (107.286 us; speedup 1.0000x reference)
//
#include <hip/hip_runtime.h>

// FidelityModelWithSAE: out[m] = energy[m] + sum_{atoms a in mol m} sae[numbers[a]+200]
// numbers in [0,119) -> gather index in [200,318]; mol_idx is SORTED.
//
// Memory-bound: 64.5 MB fixed traffic, ~10.3 us floor at 6.3 TB/s.
// v2 (resubmit; previous round failed on container acquire, not on the kernel):
//  - Single-shot: each lane owns 16 CONTIGUOUS atoms (4x int4 of numbers +
//    4x int4 of mol_idx issued up front, 8 dwordx4 in flight). The cross-lane
//    segmented suffix-reduce runs ONCE per lane (12 ds_bpermute) instead of
//    once per grid-stride iteration (48) -> 4x less shuffle traffic.
//  - 32-way bank-replicated SAE table in LDS (119*32 floats, 15.2 KB):
//    gather index n*32 + (lane&31) -> bank == lane&31 -> conflict-free
//    (the 2-way lane / lane+32 aliasing is free on CDNA4).
//  - Intra-lane run merge over 16 sorted atoms; mol boundaries inside a lane
//    go straight to atomicAdd (~61K chip-wide); wave-level run heads add
//    after the suffix-reduce (~74K). ~135K atomics over 65K addresses total.
//  - Hardening vs last round: wave-UNIFORM trip count (predication via key=-1)
//    so every lane always executes the __shfl calls with a full exec mask,
//    even if n_chunks were not a multiple of stride.

#define SAE_WINDOW 119      // numbers in [0,119)
#define SAE_SHIFT  200      // FIDELITY_LEVEL * FIDELITY_OFFSET

__global__ __launch_bounds__(256)
void sae_segsum_kernel(const float* __restrict__ sae,
                       const int*   __restrict__ numbers,
                       const int*   __restrict__ mol_idx,
                       float*       __restrict__ out,
                       int n_vec4, int n_chunks, int stride)
{
    // 32-way bank replication: s_sae[n*32 + b] holds sae[SAE_SHIFT+n] for all b.
    __shared__ float s_sae[SAE_WINDOW * 32];
    const int tid = threadIdx.x;
    for (int idx = tid; idx < SAE_WINDOW * 32; idx += 256)
        s_sae[idx] = sae[SAE_SHIFT + (idx >> 5)];
    __syncthreads();

    const int lane = tid & 63;
    const float* __restrict__ s_lane = s_sae + (lane & 31);

    const int4* __restrict__ num4 = (const int4*)numbers;
    const int4* __restrict__ mol4 = (const int4*)mol_idx;

    const int gtid  = blockIdx.x * blockDim.x + tid;
    const int iters = (n_chunks + stride - 1) / stride;  // uniform across lanes

    // One chunk = 4 consecutive int4s = 16 contiguous atoms per lane.
    // At N_ATOMS = 2^23 with grid 2048x256: iters == 1.
    for (int it = 0; it < iters; ++it) {
        const int c = gtid + it * stride;

        int   key = -1;     // stays -1 for out-of-range lanes (never committed)
        float val = 0.0f;

        if (c < n_chunks) {
            const int base = c << 2;

            int4 nv[4], mv[4];
            #pragma unroll
            for (int j = 0; j < 4; ++j) {
                if (base + j < n_vec4) {
                    nv[j] = num4[base + j];
                    mv[j] = mol4[base + j];
                } else {
                    // pad: key -1 runs are suffixes of the lane's chunk and are
                    // never atomically committed (guards below).
                    nv[j] = make_int4(0, 0, 0, 0);
                    mv[j] = make_int4(-1, -1, -1, -1);
                }
            }

            // Intra-lane run-length merge over 16 sorted atoms.
            int   cur = mv[0].x;
            float acc = s_lane[nv[0].x << 5];

            #define MERGE_STEP(mk, nk)                                    \
                do {                                                      \
                    const int   _m = (mk);                                \
                    const float _v = s_lane[(nk) << 5];                   \
                    if (_m == cur) acc += _v;                             \
                    else {                                                \
                        if (cur >= 0) atomicAdd(&out[cur], acc);          \
                        cur = _m; acc = _v;                               \
                    }                                                     \
                } while (0)

            MERGE_STEP(mv[0].y, nv[0].y);
            MERGE_STEP(mv[0].z, nv[0].z);
            MERGE_STEP(mv[0].w, nv[0].w);
            #pragma unroll
            for (int j = 1; j < 4; ++j) {
                MERGE_STEP(mv[j].x, nv[j].x);
                MERGE_STEP(mv[j].y, nv[j].y);
                MERGE_STEP(mv[j].z, nv[j].z);
                MERGE_STEP(mv[j].w, nv[j].w);
            }
            #undef MERGE_STEP

            key = cur;
            val = acc;
        }

        // Cross-lane segmented suffix reduce: tail keys are non-decreasing
        // across the wave (lanes cover consecutive 16-atom chunks); after 6
        // steps each run-head lane holds its run's full sum. All 64 lanes
        // execute these shuffles (trip count is wave-uniform).
        #pragma unroll
        for (int d = 1; d < 64; d <<= 1) {
            const int   okey = __shfl_down(key, d, 64);
            const float oval = __shfl_down(val, d, 64);
            if ((lane + d) < 64 && okey == key) val += oval;
        }
        const int pkey = __shfl_up(key, 1, 64);
        if (key >= 0 && (lane == 0 || pkey != key)) {
            atomicAdd(&out[key], val);
        }
    }
}

// Fallback for a non-multiple-of-4 atom tail (not hit at N_ATOMS = 2^23).
__global__ void sae_tail_kernel(const float* __restrict__ sae,
                                const int*   __restrict__ numbers,
                                const int*   __restrict__ mol_idx,
                                float*       __restrict__ out,
                                int start, int n_atoms)
{
    int i = start + blockIdx.x * blockDim.x + threadIdx.x;
    if (i < n_atoms) {
        atomicAdd(&out[mol_idx[i]], sae[numbers[i] + SAE_SHIFT]);
    }
}

extern "C" void kernel_launch(void* const* d_in, const int* in_sizes, int n_in,
                              void* d_out, int out_size, void* d_ws, size_t ws_size,
                              hipStream_t stream) {
    const float* energy  = (const float*)d_in[0];   // [N_MOL]
    const float* sae     = (const float*)d_in[1];   // [518]
    const int*   numbers = (const int*)d_in[2];     // [N_ATOMS]
    const int*   mol_idx = (const int*)d_in[3];     // [N_ATOMS]
    float*       out     = (float*)d_out;           // [N_MOL]

    const int n_atoms  = in_sizes[2];
    const int n_vec4   = n_atoms >> 2;
    const int n_chunks = (n_vec4 + 3) >> 2;         // 16 atoms per chunk

    // out <- energy (stream-ordered; atomics below accumulate on top)
    hipMemcpyAsync(out, energy, (size_t)out_size * sizeof(float),
                   hipMemcpyDeviceToDevice, stream);

    const int block = 256;
    int grid = (n_chunks + block - 1) / block;
    if (grid > 2048) grid = 2048;                   // 8 blocks/CU cap
    const int stride = grid * block;                // 2^23 atoms -> exactly 1 pass

    sae_segsum_kernel<<<grid, block, 0, stream>>>(sae, numbers, mol_idx, out,
                                                  n_vec4, n_chunks, stride);

    const int rem = n_atoms & 3;
    if (rem) {  // size-dependent (constant per problem), graph-safe
        sae_tail_kernel<<<1, 64, 0, stream>>>(sae, numbers, mol_idx, out,
                                              n_vec4 << 2, n_atoms);
    }
}

// Round 3
// 103.249 us; speedup vs baseline: 1.0391x; 1.0391x over previous
//
#include <hip/hip_runtime.h>

// FidelityModelWithSAE: out[m] = energy[m] + sum_{atoms a in mol m} sae[numbers[a]+200]
// numbers in [0,119) -> gather index in [200,318]; mol_idx is SORTED.
//
// Memory-bound: 64.5 MB fixed traffic, ~10.3 us floor at 6.3 TB/s. The two
// 256 MiB harness poison-fills (~82 us) dominate dur_us and are untouchable.
//
// v3 — post-mortem of v2 (107.3 us, REGRESSED): 16-atoms-per-lane broke wave
// coalescing (64B-stride lane pattern, 4KB span per dwordx4). Revert to v1's
// proven coalesced grid-stride layout (4 atoms/lane/iter, contiguous across
// the wave), and apply the two orthogonal fixes separately:
//  - 32-way bank-replicated SAE table (119*32 floats = 15.2 KB LDS): gather
//    at s_sae[n*32 + (lane&31)] -> bank == lane&31 -> conflict-free (the
//    2-way lane/lane+32 aliasing is free on CDNA4). v1's flat 119-float table
//    had ~4-6-way random conflicts on every gather.
//  - Ballot-based segmented suffix reduce: run extents from 1 shfl_up +
//    1 ballot + ctz (keys sorted => run of lane i ends at next head-1), then
//    6 val-only shfl_down. 13 -> 8 cross-lane ops per iteration.
// 8 blocks/CU x 15.2 KB = 122 KB < 160 KB LDS -> full 32-wave occupancy kept.

#define SAE_WINDOW 119      // numbers in [0,119)
#define SAE_SHIFT  200      // FIDELITY_LEVEL * FIDELITY_OFFSET

__global__ __launch_bounds__(256)
void sae_segsum_kernel(const float* __restrict__ sae,
                       const int*   __restrict__ numbers,
                       const int*   __restrict__ mol_idx,
                       float*       __restrict__ out,
                       int n_vec4, int stride)
{
    // 32-way bank replication: s_sae[n*32 + b] holds sae[SAE_SHIFT+n] for all b.
    __shared__ float s_sae[SAE_WINDOW * 32];
    const int tid = threadIdx.x;
    for (int idx = tid; idx < SAE_WINDOW * 32; idx += 256)
        s_sae[idx] = sae[SAE_SHIFT + (idx >> 5)];
    __syncthreads();

    const int lane = tid & 63;
    const float* __restrict__ s_lane = s_sae + (lane & 31);

    const int4* __restrict__ num4 = (const int4*)numbers;
    const int4* __restrict__ mol4 = (const int4*)mol_idx;

    const int gtid  = blockIdx.x * blockDim.x + tid;
    const int iters = (n_vec4 + stride - 1) / stride;   // wave-uniform

    for (int it = 0; it < iters; ++it) {
        const int i = gtid + it * stride;
        int   key = -1;       // invalid marker for out-of-range lanes
        float val = 0.0f;

        if (i < n_vec4) {
            const int4 n = num4[i];          // coalesced: 16B/lane, 1KB/wave
            const int4 m = mol4[i];
            const float v0 = s_lane[n.x << 5];   // conflict-free gathers
            const float v1 = s_lane[n.y << 5];
            const float v2 = s_lane[n.z << 5];
            const float v3 = s_lane[n.w << 5];

            // intra-lane run-length merge over 4 contiguous (sorted) mol ids
            int cur = m.x; float acc = v0;
            if (m.y == cur) acc += v1; else { atomicAdd(&out[cur], acc); cur = m.y; acc = v1; }
            if (m.z == cur) acc += v2; else { atomicAdd(&out[cur], acc); cur = m.z; acc = v2; }
            if (m.w == cur) acc += v3; else { atomicAdd(&out[cur], acc); cur = m.w; acc = v3; }
            key = cur; val = acc;   // tail run kept for cross-lane merge
        }

        // Run extents once per iteration: keys are non-decreasing across the
        // wave, so lane i's run ends at (next head lane above i) - 1.
        const int  pkey = __shfl_up(key, 1, 64);
        const bool head = (lane == 0) || (pkey != key);
        const unsigned long long bmask = __ballot(head);
        const unsigned long long above = bmask & ~((2ULL << lane) - 1ULL);
        const int e = above ? (__builtin_ctzll(above) - 1) : 63;

        // Val-only segmented suffix reduce: after 6 steps each head lane
        // holds the full sum of its run [lane, e].
        #pragma unroll
        for (int d = 1; d < 64; d <<= 1) {
            const float oval = __shfl_down(val, d, 64);
            if (lane + d <= e) val += oval;
        }
        if (head && key >= 0) {
            atomicAdd(&out[key], val);
        }
    }
}

// Fallback for a non-multiple-of-4 atom tail (not hit at N_ATOMS = 2^23).
__global__ void sae_tail_kernel(const float* __restrict__ sae,
                                const int*   __restrict__ numbers,
                                const int*   __restrict__ mol_idx,
                                float*       __restrict__ out,
                                int start, int n_atoms)
{
    int i = start + blockIdx.x * blockDim.x + threadIdx.x;
    if (i < n_atoms) {
        atomicAdd(&out[mol_idx[i]], sae[numbers[i] + SAE_SHIFT]);
    }
}

extern "C" void kernel_launch(void* const* d_in, const int* in_sizes, int n_in,
                              void* d_out, int out_size, void* d_ws, size_t ws_size,
                              hipStream_t stream) {
    const float* energy  = (const float*)d_in[0];   // [N_MOL]
    const float* sae     = (const float*)d_in[1];   // [518]
    const int*   numbers = (const int*)d_in[2];     // [N_ATOMS]
    const int*   mol_idx = (const int*)d_in[3];     // [N_ATOMS]
    float*       out     = (float*)d_out;           // [N_MOL]

    const int n_atoms = in_sizes[2];
    const int n_vec4  = n_atoms >> 2;

    // out <- energy (stream-ordered; atomics below accumulate on top)
    hipMemcpyAsync(out, energy, (size_t)out_size * sizeof(float),
                   hipMemcpyDeviceToDevice, stream);

    const int block  = 256;
    const int grid   = 2048;               // 8 blocks/CU -> full 32-wave occupancy
    const int stride = grid * block;       // 524288 threads; 2^21 int4s -> 4 iters

    sae_segsum_kernel<<<grid, block, 0, stream>>>(sae, numbers, mol_idx, out,
                                                  n_vec4, stride);

    const int rem = n_atoms & 3;
    if (rem) {  // size-dependent (constant per problem), graph-safe
        sae_tail_kernel<<<1, 64, 0, stream>>>(sae, numbers, mol_idx, out,
                                              n_vec4 << 2, n_atoms);
    }
}

// Round 4
// 102.661 us; speedup vs baseline: 1.0450x; 1.0057x over previous
//
#include <hip/hip_runtime.h>

// FidelityModelWithSAE: out[m] = energy[m] + sum_{atoms a in mol m} sae[numbers[a]+200]
// numbers in [0,119) -> gather index in [200,318]; mol_idx is SORTED.
//
// Memory-bound: 64.5 MB fixed traffic, ~10.3 us floor at 6.3 TB/s. The two
// 256 MiB harness poison-fills (~83 us) dominate dur_us and are untouchable.
//
// v4 — post-mortem of v3 (kernel-slice ~20 us, neutral): bank-replication and
// ballot-reduce were not the bottleneck. The runtime grid-stride loop was:
// the compiler cannot unroll a runtime trip count, so each iteration's two
// dwordx4 loads are waited on (vmcnt(0)) inside that iteration -> per-thread
// MLP ~2 and 4 serial HBM round-trips (~4000 cyc/thread, latency-bound).
// Fix: compile-time fast path (n_vec4 == 4*stride holds exactly at 2^23
// atoms): issue ALL 8 dwordx4 loads up front (MLP=8), then process 4 quads;
// the compiler emits vmcnt(6/4/2) partial waits and overlaps HBM latency
// with the gather/merge/reduce chain. __launch_bounds__(256,4): <=128 VGPR,
// 16 waves/CU; in-flight 16 waves x 8KB = 128KB >> ~9KB latency-BW product.

#define SAE_WINDOW 119      // numbers in [0,119)
#define SAE_SHIFT  200      // FIDELITY_LEVEL * FIDELITY_OFFSET

__device__ __forceinline__ void process_quad(const int4 n, const int4 m,
                                             const float* __restrict__ s_lane,
                                             float* __restrict__ out,
                                             const int lane)
{
    // conflict-free gathers: bank == lane&31 by 32-way replication
    const float v0 = s_lane[n.x << 5];
    const float v1 = s_lane[n.y << 5];
    const float v2 = s_lane[n.z << 5];
    const float v3 = s_lane[n.w << 5];

    // intra-lane run-length merge over 4 contiguous (sorted) mol ids
    int cur = m.x; float acc = v0;
    if (m.y == cur) acc += v1; else { atomicAdd(&out[cur], acc); cur = m.y; acc = v1; }
    if (m.z == cur) acc += v2; else { atomicAdd(&out[cur], acc); cur = m.z; acc = v2; }
    if (m.w == cur) acc += v3; else { atomicAdd(&out[cur], acc); cur = m.w; acc = v3; }

    int   key = cur;
    float val = acc;

    // Run extents: keys are non-decreasing across the wave, so lane i's run
    // ends at (next head lane above i) - 1.
    const int  pkey = __shfl_up(key, 1, 64);
    const bool head = (lane == 0) || (pkey != key);
    const unsigned long long bmask = __ballot(head);
    const unsigned long long above = bmask & ~((2ULL << lane) - 1ULL);
    const int e = above ? (__builtin_ctzll(above) - 1) : 63;

    // Val-only segmented suffix reduce: head lane ends with its run's sum.
    #pragma unroll
    for (int d = 1; d < 64; d <<= 1) {
        const float oval = __shfl_down(val, d, 64);
        if (lane + d <= e) val += oval;
    }
    if (head && key >= 0) {
        atomicAdd(&out[key], val);
    }
}

__global__ __launch_bounds__(256, 4)
void sae_segsum_kernel(const float* __restrict__ sae,
                       const int*   __restrict__ numbers,
                       const int*   __restrict__ mol_idx,
                       float*       __restrict__ out,
                       int n_vec4, int stride)
{
    // 32-way bank replication: s_sae[n*32 + b] holds sae[SAE_SHIFT+n] for all b.
    __shared__ float s_sae[SAE_WINDOW * 32];
    const int tid = threadIdx.x;
    for (int idx = tid; idx < SAE_WINDOW * 32; idx += 256)
        s_sae[idx] = sae[SAE_SHIFT + (idx >> 5)];
    __syncthreads();

    const int lane = tid & 63;
    const float* __restrict__ s_lane = s_sae + (lane & 31);

    const int4* __restrict__ num4 = (const int4*)numbers;
    const int4* __restrict__ mol4 = (const int4*)mol_idx;

    const int gtid = blockIdx.x * blockDim.x + tid;

    if (n_vec4 == (stride << 2)) {
        // Fast path (taken at N_ATOMS = 2^23): compile-time 4 quads/thread.
        // All 8 dwordx4 loads issued before any use -> MLP=8 per thread.
        int4 n[4], m[4];
        #pragma unroll
        for (int j = 0; j < 4; ++j) {
            n[j] = num4[gtid + j * stride];   // coalesced: 1KB/wave/instr
            m[j] = mol4[gtid + j * stride];
        }
        #pragma unroll
        for (int j = 0; j < 4; ++j)
            process_quad(n[j], m[j], s_lane, out, lane);
    } else {
        // Generic guarded path (wave-uniform trip count, predication via -1).
        const int iters = (n_vec4 + stride - 1) / stride;
        for (int it = 0; it < iters; ++it) {
            const int i = gtid + it * stride;
            int4 n = make_int4(0, 0, 0, 0);
            int4 m = make_int4(-1, -1, -1, -1);
            if (i < n_vec4) { n = num4[i]; m = mol4[i]; }
            // key<0 lanes: gathers read s_sae[0] (harmless), no atomics commit
            // (cur<0 guard below is inside process_quad's merge? no — guard here)
            if (i < n_vec4) {
                process_quad(n, m, s_lane, out, lane);
            } else {
                // still participate in wave ops with key=-1
                int key = -1; float val = 0.0f;
                const int  pkey = __shfl_up(key, 1, 64); (void)pkey;
                const unsigned long long bmask = __ballot(true);
                (void)bmask;
                #pragma unroll
                for (int d = 1; d < 64; d <<= 1) {
                    const float oval = __shfl_down(val, d, 64); (void)oval;
                }
            }
        }
    }
}

// Fallback for a non-multiple-of-4 atom tail (not hit at N_ATOMS = 2^23).
__global__ void sae_tail_kernel(const float* __restrict__ sae,
                                const int*   __restrict__ numbers,
                                const int*   __restrict__ mol_idx,
                                float*       __restrict__ out,
                                int start, int n_atoms)
{
    int i = start + blockIdx.x * blockDim.x + threadIdx.x;
    if (i < n_atoms) {
        atomicAdd(&out[mol_idx[i]], sae[numbers[i] + SAE_SHIFT]);
    }
}

extern "C" void kernel_launch(void* const* d_in, const int* in_sizes, int n_in,
                              void* d_out, int out_size, void* d_ws, size_t ws_size,
                              hipStream_t stream) {
    const float* energy  = (const float*)d_in[0];   // [N_MOL]
    const float* sae     = (const float*)d_in[1];   // [518]
    const int*   numbers = (const int*)d_in[2];     // [N_ATOMS]
    const int*   mol_idx = (const int*)d_in[3];     // [N_ATOMS]
    float*       out     = (float*)d_out;           // [N_MOL]

    const int n_atoms = in_sizes[2];
    const int n_vec4  = n_atoms >> 2;

    // out <- energy (stream-ordered; atomics below accumulate on top)
    hipMemcpyAsync(out, energy, (size_t)out_size * sizeof(float),
                   hipMemcpyDeviceToDevice, stream);

    const int block  = 256;
    const int grid   = 2048;               // 524288 threads
    const int stride = grid * block;       // n_vec4 = 4*stride exactly -> fast path

    sae_segsum_kernel<<<grid, block, 0, stream>>>(sae, numbers, mol_idx, out,
                                                  n_vec4, stride);

    const int rem = n_atoms & 3;
    if (rem) {  // size-dependent (constant per problem), graph-safe
        sae_tail_kernel<<<1, 64, 0, stream>>>(sae, numbers, mol_idx, out,
                                              n_vec4 << 2, n_atoms);
    }
}

// Round 5
// 100.258 us; speedup vs baseline: 1.0701x; 1.0240x over previous
//
#include <hip/hip_runtime.h>

// FidelityModelWithSAE: out[m] = energy[m] + sum_{atoms a in mol m} sae[numbers[a]+200]
// numbers in [0,119) -> gather index in [200,318]; mol_idx is SORTED.
//
// FINAL (v5 = revert to best-measured v1, 100.698 us).
// Session evidence: three structurally different kernels (v1 runtime loop /
// v3 bank-replicated LDS + ballot reduce / v4 full MLP=8 unroll) all measure
// 100.7-103.2 us, with the two 256 MiB harness poison-fills fixed at ~82-84 us
// of that. The controllable slice does not respond to kernel structure:
// it is ~10.3 us of irreducible HBM traffic (64.5 MB @ ~6.3 TB/s) + ~2 us
// D2D blit launch for the energy seed + fill/dispatch jitter. v1 is the
// empirical minimum, so it is restored verbatim as the final artifact.
//
// Strategy: memory-bound.
//  - out <- energy via d2d memcpyAsync (graph-safe).
//  - int4 loads of numbers+mol_idx (16B/lane each, coalesced).
//  - SAE window (119 floats) in LDS.
//  - per-lane run merge of 4 contiguous atoms (intra-lane boundary -> direct
//    atomic, ~65K total chip-wide), keep tail run.
//  - cross-lane segmented suffix-reduce over sorted tail keys via 6x shfl_down;
//    only run-head lanes atomicAdd (~150K atomics total over 65K addresses).

#define SAE_WINDOW 119      // numbers in [0,119)
#define SAE_SHIFT  200      // FIDELITY_LEVEL * FIDELITY_OFFSET

__global__ __launch_bounds__(256)
void sae_segsum_kernel(const float* __restrict__ sae,
                       const int*   __restrict__ numbers,
                       const int*   __restrict__ mol_idx,
                       float*       __restrict__ out,
                       int n_vec4, int stride)
{
    __shared__ float s_sae[128];
    const int tid  = threadIdx.x;
    if (tid < SAE_WINDOW) s_sae[tid] = sae[SAE_SHIFT + tid];
    __syncthreads();

    const int lane = tid & 63;
    const int gtid = blockIdx.x * blockDim.x + tid;

    const int4* __restrict__ num4 = (const int4*)numbers;
    const int4* __restrict__ mol4 = (const int4*)mol_idx;

    const int iters = (n_vec4 + stride - 1) / stride;  // uniform across all lanes

    for (int it = 0; it < iters; ++it) {
        const int i = gtid + it * stride;
        int   key = -1;       // invalid marker for out-of-range lanes
        float val = 0.0f;

        if (i < n_vec4) {
            const int4 n = num4[i];
            const int4 m = mol4[i];
            const float v0 = s_sae[n.x];
            const float v1 = s_sae[n.y];
            const float v2 = s_sae[n.z];
            const float v3 = s_sae[n.w];

            // intra-lane run-length merge over 4 contiguous (sorted) mol ids
            int cur = m.x; float acc = v0;
            if (m.y == cur) acc += v1; else { atomicAdd(&out[cur], acc); cur = m.y; acc = v1; }
            if (m.z == cur) acc += v2; else { atomicAdd(&out[cur], acc); cur = m.z; acc = v2; }
            if (m.w == cur) acc += v3; else { atomicAdd(&out[cur], acc); cur = m.w; acc = v3; }
            key = cur; val = acc;   // tail run kept for cross-lane merge
        }

        // cross-lane segmented suffix reduce: tail keys are non-decreasing across
        // the wave; after 6 steps each run-head lane holds its full run sum.
        #pragma unroll
        for (int d = 1; d < 64; d <<= 1) {
            const int   okey = __shfl_down(key, d, 64);
            const float oval = __shfl_down(val, d, 64);
            if ((lane + d) < 64 && okey == key) val += oval;
        }
        const int pkey = __shfl_up(key, 1, 64);
        if (key >= 0 && (lane == 0 || pkey != key)) {
            atomicAdd(&out[key], val);
        }
    }
}

// Fallback for a non-multiple-of-4 atom tail (not hit at N_ATOMS = 2^23).
__global__ void sae_tail_kernel(const float* __restrict__ sae,
                                const int*   __restrict__ numbers,
                                const int*   __restrict__ mol_idx,
                                float*       __restrict__ out,
                                int start, int n_atoms)
{
    int i = start + blockIdx.x * blockDim.x + threadIdx.x;
    if (i < n_atoms) {
        atomicAdd(&out[mol_idx[i]], sae[numbers[i] + SAE_SHIFT]);
    }
}

extern "C" void kernel_launch(void* const* d_in, const int* in_sizes, int n_in,
                              void* d_out, int out_size, void* d_ws, size_t ws_size,
                              hipStream_t stream) {
    const float* energy  = (const float*)d_in[0];   // [N_MOL]
    const float* sae     = (const float*)d_in[1];   // [518]
    const int*   numbers = (const int*)d_in[2];     // [N_ATOMS]
    const int*   mol_idx = (const int*)d_in[3];     // [N_ATOMS]
    float*       out     = (float*)d_out;           // [N_MOL]

    const int n_atoms = in_sizes[2];
    const int n_vec4  = n_atoms >> 2;

    // out <- energy (stream-ordered; atomics below accumulate on top)
    hipMemcpyAsync(out, energy, (size_t)out_size * sizeof(float),
                   hipMemcpyDeviceToDevice, stream);

    const int block  = 256;
    const int grid   = 2048;               // 8 blocks/CU -> full 32-wave occupancy
    const int stride = grid * block;       // 524288 threads; 2^21 int4s -> 4 iters

    sae_segsum_kernel<<<grid, block, 0, stream>>>(sae, numbers, mol_idx, out,
                                                  n_vec4, stride);

    const int rem = n_atoms & 3;
    if (rem) {  // size-dependent (constant per problem), graph-safe
        sae_tail_kernel<<<1, 64, 0, stream>>>(sae, numbers, mol_idx, out,
                                              n_vec4 << 2, n_atoms);
    }
}